// Round 1
// baseline (789.143 us; speedup 1.0000x reference)
//
#include <hip/hip_runtime.h>
#include <math.h>

#define HOP 256
#define NFFT 2048
#define PI2F 6.28318530717958647692f

// Fused: STFT frame -> |rfft| -> autocorr over frequency -> peak -> f0[t]
// One block (256 threads = 4 waves) per frame.
__global__ __launch_bounds__(256) void pitch_main(const float* __restrict__ audio,
                                                  int n, float* __restrict__ f0) {
  const int t   = blockIdx.x;
  const int tid = threadIdx.x;

  __shared__ float re[2048];
  __shared__ float im[2048];
  __shared__ float twc[1024];
  __shared__ float tws[1024];
  __shared__ float M [1792];   // magnitudes, zero-padded past 1024
  __shared__ float M1[1792];   // M shifted by 1 (M1[i] = M[i+1]) for aligned b128 reads
  __shared__ float Racc[4][512];
  __shared__ float R[513];     // R[lag] for lag 1..512 (R[512] forced 0 = mask)
  __shared__ int   hasPeak;

  // ---- twiddle table tw[m] = exp(-i 2pi m / 2048) ----
  for (int m = tid; m < 1024; m += 256) {
    float ang = -PI2F * (float)m / (float)NFFT;
    float s, c;
    sincosf(ang, &s, &c);
    twc[m] = c; tws[m] = s;
  }

  // ---- load frame with reflect padding + periodic Hann window ----
  const int base = t * HOP - (NFFT / 2);
  for (int i = tid; i < NFFT; i += 256) {
    int j = base + i;
    j = (j < 0) ? -j : j;
    j = (j >= n) ? (2 * n - 2 - j) : j;
    float w = 0.5f * (1.0f - cosf(PI2F * (float)i / (float)NFFT));
    re[i] = audio[j] * w;
    im[i] = 0.0f;
  }
  if (tid == 0) hasPeak = 0;
  __syncthreads();

  // ---- radix-2 DIF FFT (in place, output bit-reversed) ----
  for (int lg = 11; lg >= 1; --lg) {
    const int half  = 1 << (lg - 1);
    const int tstep = NFFT >> lg;
    for (int b = tid; b < 1024; b += 256) {
      const int j  = b & (half - 1);
      const int i0 = ((b >> (lg - 1)) << lg) + j;
      const int i1 = i0 + half;
      float ur = re[i0], ui = im[i0];
      float vr = re[i1], vi = im[i1];
      re[i0] = ur + vr; im[i0] = ui + vi;
      float dr = ur - vr, di = ui - vi;
      const int twi = j * tstep;
      float c = twc[twi], s = tws[twi];
      re[i1] = dr * c - di * s;
      im[i1] = dr * s + di * c;
    }
    __syncthreads();
  }

  // ---- magnitudes: X[k] sits at bit-reversed position ----
  for (int k = tid; k < 1792; k += 256) {
    float v = 0.0f;
    if (k <= 1024) {
      const int p = (int)(__brev((unsigned)k) >> 21);
      float a = re[p], b2 = im[p];
      v = sqrtf(a * a + b2 * b2);
    }
    M[k] = v;
  }
  __syncthreads();
  for (int i = tid; i < 1792; i += 256) {
    M1[i] = (i + 1 < 1792) ? M[i + 1] : 0.0f;
  }
  __syncthreads();

  // ---- direct autocorr: r[lag] = sum_k M[k]*M[k+lag], lag = 1..512 ----
  // 4 waves each own a k-quarter; each lane owns 8 consecutive lags
  // lag = 8*lane + 1 + m  (m = 0..7); shifted operand from M1, 16B-aligned.
  {
    const int wave = tid >> 6;
    const int lane = tid & 63;
    float acc[8] = {0.f,0.f,0.f,0.f,0.f,0.f,0.f,0.f};
    const float4* M4  = (const float4*)M;
    const float4* M14 = (const float4*)M1;
    const int k0 = wave << 8;              // 256 k's per wave
    for (int kc = 0; kc < 256; kc += 8) {
      const int k = k0 + kc;
      const float4 ua = M4[k >> 2];
      const float4 ub = M4[(k >> 2) + 1];
      const float u[8] = {ua.x, ua.y, ua.z, ua.w, ub.x, ub.y, ub.z, ub.w};
      const int sb = (k + (lane << 3)) >> 2;
      const float4 v0 = M14[sb], v1 = M14[sb + 1], v2 = M14[sb + 2], v3 = M14[sb + 3];
      const float v[16] = {v0.x,v0.y,v0.z,v0.w, v1.x,v1.y,v1.z,v1.w,
                           v2.x,v2.y,v2.z,v2.w, v3.x,v3.y,v3.z,v3.w};
      #pragma unroll
      for (int m2 = 0; m2 < 8; ++m2) {
        float a = acc[m2];
        #pragma unroll
        for (int q = 0; q < 8; ++q) a += u[q] * v[m2 + q];
        acc[m2] = a;
      }
    }
    #pragma unroll
    for (int m2 = 0; m2 < 8; ++m2) Racc[wave][(lane << 3) + m2] = acc[m2];
  }
  __syncthreads();

  // reduce k-quarters; mask lag 512 (reference: valid lags are 1..511)
  for (int idx = tid; idx < 512; idx += 256) {
    float rsum = Racc[0][idx] + Racc[1][idx] + Racc[2][idx] + Racc[3][idx];
    R[idx + 1] = (idx == 511) ? 0.0f : rsum;
  }
  __syncthreads();

  // ---- peak detect: exists i in [2,511] with R[i] > R[i-1] && R[i] > R[i+1]
  // (i in [512,1023] of the reference ac are all-zero -> never peaks)
  {
    int cond = 0;
    for (int i2 = 2 + tid; i2 < 512; i2 += 256) {
      const float c0 = R[i2];
      if (c0 > R[i2 - 1] && c0 > R[i2 + 1]) cond = 1;
    }
    if (__any(cond)) {
      if ((tid & 63) == 0) hasPeak = 1;
    }
  }
  __syncthreads();
  if (tid == 0) f0[t] = hasPeak ? 50.0f : 0.0f;
}

// Median-of-5 smoothing with edge clamp (jnp.pad mode='edge').
__global__ __launch_bounds__(256) void median5_kernel(const float* __restrict__ f0,
                                                      float* __restrict__ out, int T) {
  const int t = blockIdx.x * blockDim.x + threadIdx.x;
  if (t >= T) return;
  float v[5];
  #pragma unroll
  for (int m = 0; m < 5; ++m) {
    int idx = t + m - 2;
    idx = idx < 0 ? 0 : (idx > T - 1 ? T - 1 : idx);
    v[m] = f0[idx];
  }
  // optimal 9-comparator sorting network for 5 elements
  #define SW(a,b) { float lo = fminf(v[a], v[b]); float hi = fmaxf(v[a], v[b]); v[a] = lo; v[b] = hi; }
  SW(0,1); SW(3,4); SW(2,4); SW(2,3); SW(1,4); SW(0,3); SW(0,2); SW(1,3); SW(1,2);
  #undef SW
  out[t] = v[2];
}

extern "C" void kernel_launch(void* const* d_in, const int* in_sizes, int n_in,
                              void* d_out, int out_size, void* d_ws, size_t ws_size,
                              hipStream_t stream) {
  const float* audio = (const float*)d_in[0];
  const int n = in_sizes[0];          // 2097152
  const int T = n / HOP + 1;          // 8193
  float* f0 = (float*)d_ws;           // T floats of scratch

  pitch_main<<<T, 256, 0, stream>>>(audio, n, f0);
  median5_kernel<<<(T + 255) / 256, 256, 0, stream>>>(f0, (float*)d_out, T);
}

// Round 2
// 423.826 us; speedup vs baseline: 1.8620x; 1.8620x over previous
//
#include <hip/hip_runtime.h>
#include <math.h>

#define HOP 256
#define NFFT 2048
#define PI2F 6.28318530717958647692f
// bank-spread padding: injective, turns stride-32-dword patterns conflict-free
#define PADI(i) ((i) + ((i) >> 5))

// Fused: STFT frame -> |rfft| -> autocorr over frequency -> peak -> f0[t]
// One block (256 threads = 4 waves) per frame.
__global__ __launch_bounds__(256) void pitch_main(const float* __restrict__ audio,
                                                  int n, float* __restrict__ f0) {
  const int t   = blockIdx.x;
  const int tid = threadIdx.x;

  // pooled LDS with lifetime overlay (35.7 KB -> 4 blocks/CU)
  __shared__ float pool[8928];
  __shared__ int   hasPeak;
  float* re  = pool;          // PADI(2047)=2110 -> 2112 floats
  float* im  = pool + 2112;   // 2112
  float* twc = pool + 4224;   // 1056 (PADI(1023)=1054)
  float* tws = pool + 5280;   // 1056
  float* M   = pool + 6336;   // 1040  (magnitudes, natural order; zero past 1024)
  float* M1  = pool + 7376;   // 1552  (M shifted by 1: M1[i] = M[i+1], zero-padded)
  // aliases over re[] (dead after magnitude step):
  float* Racc = pool;         // 4 * 256 partial autocorr
  float* R    = pool + 1024;  // R[lag], lag 1..512 (R[512] masked to 0)

  // ---- twiddle table tw[m] = exp(-i 2pi m / 2048), bank-padded ----
  for (int m = tid; m < 1024; m += 256) {
    float ang = -PI2F * (float)m / (float)NFFT;
    float s, c;
    sincosf(ang, &s, &c);
    twc[PADI(m)] = c; tws[PADI(m)] = s;
  }

  // ---- load frame with reflect padding + periodic Hann window ----
  const int base = t * HOP - (NFFT / 2);
  for (int i = tid; i < NFFT; i += 256) {
    int j = base + i;
    j = (j < 0) ? -j : j;
    j = (j >= n) ? (2 * n - 2 - j) : j;
    float w = 0.5f * (1.0f - cosf(PI2F * (float)i / (float)NFFT));
    re[PADI(i)] = audio[j] * w;
    im[PADI(i)] = 0.0f;
  }
  if (tid == 0) hasPeak = 0;
  __syncthreads();

  // ---- radix-2 DIF FFT (in place, padded addressing, output bit-reversed) ----
  for (int lg = 11; lg >= 1; --lg) {
    const int half  = 1 << (lg - 1);
    const int tstep = NFFT >> lg;
    for (int b = tid; b < 1024; b += 256) {
      const int j  = b & (half - 1);
      const int i0 = ((b >> (lg - 1)) << lg) + j;
      const int a0 = PADI(i0);
      const int a1 = PADI(i0 + half);
      float ur = re[a0], ui = im[a0];
      float vr = re[a1], vi = im[a1];
      re[a0] = ur + vr; im[a0] = ui + vi;
      float dr = ur - vr, di = ui - vi;
      const int twi = PADI(j * tstep);
      float c = twc[twi], s = tws[twi];
      re[a1] = dr * c - di * s;
      im[a1] = dr * s + di * c;
    }
    __syncthreads();
  }

  // ---- magnitudes (bit-reversed gather, conflict-free via padding) ----
  for (int k = tid; k <= 1024; k += 256) {
    const int p = (int)(__brev((unsigned)k) >> 21);
    const int a = PADI(p);
    float x = re[a], y = im[a];
    float v = sqrtf(x * x + y * y);
    M[k] = v;
    if (k >= 1) M1[k - 1] = v;
  }
  for (int i = 1025 + tid; i < 1040; i += 256) M[i] = 0.0f;
  for (int i = 1024 + tid; i < 1552; i += 256) M1[i] = 0.0f;
  __syncthreads();

  // ---- direct autocorr: r[lag] = sum_k M[k]*M[k+lag], lag = 1..512 ----
  // Wave w: lag block (w>>1)*256, k-half (w&1)*512. Lane owns 4 consecutive
  // lags (stride-4-dword shifted reads = conflict-free b128 at the LDS floor);
  // M-operand is wave-uniform -> free broadcast. 12-float sliding window.
  {
    const int wave = tid >> 6;
    const int lane = tid & 63;
    const int lagbase = (wave >> 1) << 8;   // 0 or 256
    const int k0      = (wave & 1) << 9;    // 0 or 512
    const float4* M4  = (const float4*)M;
    const float4* M14 = (const float4*)M1;
    const int vb = ((k0 + lagbase) >> 2) + lane;  // float4 idx of lane's window
    float a0 = 0.f, a1 = 0.f, a2 = 0.f, a3 = 0.f;
    float4 c0 = M14[vb];
    #pragma unroll 2
    for (int kc = 0; kc < 512; kc += 8) {
      const int f = (k0 + kc) >> 2;
      const float4 u0 = M4[f];              // uniform -> broadcast
      const float4 u1 = M4[f + 1];
      const float4 c1 = M14[vb + (kc >> 2) + 1];
      const float4 c2 = M14[vb + (kc >> 2) + 2];
      const float v0=c0.x, v1=c0.y, v2=c0.z, v3=c0.w;
      const float v4=c1.x, v5=c1.y, v6=c1.z, v7=c1.w;
      const float v8=c2.x, v9=c2.y, v10=c2.z;
      a0 += u0.x*v0 + u0.y*v1 + u0.z*v2 + u0.w*v3
          + u1.x*v4 + u1.y*v5 + u1.z*v6 + u1.w*v7;
      a1 += u0.x*v1 + u0.y*v2 + u0.z*v3 + u0.w*v4
          + u1.x*v5 + u1.y*v6 + u1.z*v7 + u1.w*v8;
      a2 += u0.x*v2 + u0.y*v3 + u0.z*v4 + u0.w*v5
          + u1.x*v6 + u1.y*v7 + u1.z*v8 + u1.w*v9;
      a3 += u0.x*v3 + u0.y*v4 + u0.z*v5 + u0.w*v6
          + u1.x*v7 + u1.y*v8 + u1.z*v9 + u1.w*v10;
      c0 = c2;
    }
    // lag = lagbase + 4*lane + 1 + m ; partial for k-half (wave&1)
    ((float4*)(Racc + (wave << 8)))[lane] = make_float4(a0, a1, a2, a3);
  }
  __syncthreads();

  // reduce the two k-halves; mask lag 512 (valid lags are 1..511)
  for (int idx = tid; idx < 512; idx += 256) {
    const int h = idx >> 8, i = idx & 255;
    float s = Racc[(h << 1) * 256 + i] + Racc[((h << 1) + 1) * 256 + i];
    R[idx + 1] = (idx == 511) ? 0.0f : s;
  }
  __syncthreads();

  // ---- peak detect: exists i in [2,511] with R[i] > R[i-1] && R[i] > R[i+1]
  {
    int cond = 0;
    for (int i2 = 2 + tid; i2 < 512; i2 += 256) {
      const float c0 = R[i2];
      if (c0 > R[i2 - 1] && c0 > R[i2 + 1]) cond = 1;
    }
    if (__any(cond)) {
      if ((tid & 63) == 0) hasPeak = 1;
    }
  }
  __syncthreads();
  if (tid == 0) f0[t] = hasPeak ? 50.0f : 0.0f;
}

// Median-of-5 smoothing with edge clamp (jnp.pad mode='edge').
__global__ __launch_bounds__(256) void median5_kernel(const float* __restrict__ f0,
                                                      float* __restrict__ out, int T) {
  const int t = blockIdx.x * blockDim.x + threadIdx.x;
  if (t >= T) return;
  float v[5];
  #pragma unroll
  for (int m = 0; m < 5; ++m) {
    int idx = t + m - 2;
    idx = idx < 0 ? 0 : (idx > T - 1 ? T - 1 : idx);
    v[m] = f0[idx];
  }
  #define SW(a,b) { float lo = fminf(v[a], v[b]); float hi = fmaxf(v[a], v[b]); v[a] = lo; v[b] = hi; }
  SW(0,1); SW(3,4); SW(2,4); SW(2,3); SW(1,4); SW(0,3); SW(0,2); SW(1,3); SW(1,2);
  #undef SW
  out[t] = v[2];
}

extern "C" void kernel_launch(void* const* d_in, const int* in_sizes, int n_in,
                              void* d_out, int out_size, void* d_ws, size_t ws_size,
                              hipStream_t stream) {
  const float* audio = (const float*)d_in[0];
  const int n = in_sizes[0];          // 2097152
  const int T = n / HOP + 1;          // 8193
  float* f0 = (float*)d_ws;           // T floats of scratch

  pitch_main<<<T, 256, 0, stream>>>(audio, n, f0);
  median5_kernel<<<(T + 255) / 256, 256, 0, stream>>>(f0, (float*)d_out, T);
}

// Round 3
// 388.125 us; speedup vs baseline: 2.0332x; 1.0920x over previous
//
#include <hip/hip_runtime.h>
#include <math.h>

#define HOP 256
#define NFFT 2048
#define PI2F 6.28318530717958647692f
// bank-spread padding: injective, spreads stride-32-dword patterns across banks
#define PADI(i) ((i) + ((i) >> 5))

// ---------------- one-time tables (recomputed every launch into d_ws) --------
// win[2048]  : periodic Hann
// twc/tws[512]: e^{-j*2pi*m/1024} for the 1024-pt FFT (s = sin of NEGATIVE angle)
// unc/uns[513]: e^{-j*2pi*k/2048} untangle twiddles
__global__ __launch_bounds__(256) void precompute(float* __restrict__ win,
                                                  float* __restrict__ twc,
                                                  float* __restrict__ tws,
                                                  float* __restrict__ unc,
                                                  float* __restrict__ uns) {
  const int i = blockIdx.x * blockDim.x + threadIdx.x;
  if (i < 2048) win[i] = 0.5f * (1.0f - cosf(PI2F * (float)i / 2048.0f));
  if (i < 512) {
    float s, c;
    sincosf(-PI2F * (float)i / 1024.0f, &s, &c);
    twc[i] = c; tws[i] = s;
  }
  if (i < 513) {
    float s, c;
    sincosf(-PI2F * (float)i / 2048.0f, &s, &c);
    unc[i] = c; uns[i] = s;
  }
}

// Fused: frame -> packed 1024-pt complex FFT -> untangle to |rfft(2048)| ->
// autocorr over frequency -> peak -> f0[t]. One block (4 waves) per frame.
__global__ __launch_bounds__(256) void pitch_main(const float* __restrict__ audio,
                                                  int n, float* __restrict__ f0,
                                                  const float* __restrict__ gwin,
                                                  const float* __restrict__ gtwc,
                                                  const float* __restrict__ gtws,
                                                  const float* __restrict__ gunc,
                                                  const float* __restrict__ guns) {
  const int t   = blockIdx.x;
  const int tid = threadIdx.x;

  // pooled LDS (27.2 KB -> 5 blocks/CU)
  __shared__ float pool[6792];
  __shared__ int   hasPeak;
  float* z_re = pool;          // [0,1056)   PADI(1023)=1054
  float* z_im = pool + 1056;   // [1056,2112)
  float* twc  = pool + 2112;   // [2112,2640) PADI(511)=526
  float* tws  = pool + 2640;   // [2640,3168)
  float* unc  = pool + 3168;   // [3168,3684) 513 used, stride-1 reads
  float* uns  = pool + 3684;   // [3684,4200)
  float* M    = pool + 4200;   // [4200,5240) magnitudes, zero past 1024
  float* M1   = pool + 5240;   // [5240,6792) M shifted by 1, zero-padded
  // aliases over z arrays (dead after untangle):
  float* Racc = pool;          // 4 * 256 partial autocorr
  float* R    = pool + 1024;   // R[lag], lag 1..512 (R[512] masked)

  // ---- stage tables into LDS ----
  for (int m = tid; m < 512; m += 256) {
    twc[PADI(m)] = gtwc[m];
    tws[PADI(m)] = gtws[m];
  }
  for (int k = tid; k < 513; k += 256) { unc[k] = gunc[k]; uns[k] = guns[k]; }
  if (tid == 0) hasPeak = 0;

  // ---- load frame (reflect pad), window, pack z[i] = x[2i]*w + j*x[2i+1]*w ----
  const int base = t * HOP - (NFFT / 2);
  if (base >= 0 && base + NFFT <= n) {            // interior frame: vector loads
    const float2* au2 = (const float2*)(audio + base);
    const float2* wi2 = (const float2*)gwin;
    for (int i = tid; i < 1024; i += 256) {
      const float2 a = au2[i];
      const float2 w = wi2[i];
      z_re[PADI(i)] = a.x * w.x;
      z_im[PADI(i)] = a.y * w.y;
    }
  } else {                                        // edge frames (8 of 8193)
    for (int i = tid; i < 1024; i += 256) {
      int j0 = base + 2 * i, j1 = base + 2 * i + 1;
      j0 = (j0 < 0) ? -j0 : j0; j0 = (j0 >= n) ? (2 * n - 2 - j0) : j0;
      j1 = (j1 < 0) ? -j1 : j1; j1 = (j1 >= n) ? (2 * n - 2 - j1) : j1;
      z_re[PADI(i)] = audio[j0] * gwin[2 * i];
      z_im[PADI(i)] = audio[j1] * gwin[2 * i + 1];
    }
  }
  __syncthreads();

  // ---- 1024-pt radix-2 DIF FFT (in place, padded, output bit-reversed) ----
  for (int lg = 10; lg >= 1; --lg) {
    const int half  = 1 << (lg - 1);
    const int tstep = 1024 >> lg;
    for (int b = tid; b < 512; b += 256) {
      const int j  = b & (half - 1);
      const int i0 = ((b >> (lg - 1)) << lg) + j;
      const int a0 = PADI(i0);
      const int a1 = PADI(i0 + half);
      float ur = z_re[a0], ui = z_im[a0];
      float vr = z_re[a1], vi = z_im[a1];
      z_re[a0] = ur + vr; z_im[a0] = ui + vi;
      float dr = ur - vr, di = ui - vi;
      const int twi = PADI(j * tstep);
      float c = twc[twi], s = tws[twi];
      z_re[a1] = dr * c - di * s;
      z_im[a1] = dr * s + di * c;
    }
    __syncthreads();
  }

  // ---- untangle real-input FFT + magnitudes ----
  // Z = FFT_1024(even + j*odd); for k,m=1024-k:
  //   E = (Zk + conj Zm)/2, O = (Zk - conj Zm)/(2j), X[k] = E + e^{-j2pik/2048} O
  //   X[m] = conj(E) + (-c + j*s) conj(O)   (c,s = stored cos, -sin)
  for (int k = tid; k < 512; k += 256) {
    const int m  = (1024 - k) & 1023;
    const int pk = PADI((int)(__brev((unsigned)k) >> 22));
    const int pm = PADI((int)(__brev((unsigned)m) >> 22));
    const float ar = z_re[pk], ai = z_im[pk];
    const float br = z_re[pm], bi = z_im[pm];
    const float Er = 0.5f * (ar + br), Ei = 0.5f * (ai - bi);
    const float Or = 0.5f * (ai + bi), Oi = 0.5f * (br - ar);
    const float c = unc[k], s = uns[k];
    const float Xr = Er + c * Or - s * Oi;
    const float Xi = Ei + c * Oi + s * Or;
    const float vk = sqrtf(Xr * Xr + Xi * Xi);
    M[k] = vk;
    if (k >= 1) M1[k - 1] = vk;
    const float Yr = Er - c * Or + s * Oi;
    const float Yi = -Ei + c * Oi + s * Or;
    const float vm = sqrtf(Yr * Yr + Yi * Yi);
    const int mk = 1024 - k;                  // 513..1024, plus 1024 at k=0
    M[mk] = vm;
    M1[mk - 1] = vm;
  }
  if (tid == 0) {                             // bin 512: X[512] = conj-rot of Z[512]
    const int p = PADI((int)(__brev(512u) >> 22));
    const float x = z_re[p], y = z_im[p];
    const float v = sqrtf(x * x + y * y);
    M[512] = v; M1[511] = v;
  }
  for (int i = 1025 + tid; i < 1040; i += 256) M[i] = 0.0f;
  for (int i = 1024 + tid; i < 1552; i += 256) M1[i] = 0.0f;
  __syncthreads();

  // ---- direct autocorr: r[lag] = sum_k M[k]*M[k+lag], lag = 1..512 ----
  // Wave w: lag block (w>>1)*256, k-half (w&1)*512. Lane owns 4 consecutive
  // lags (stride-4-dword shifted reads = conflict-free b128); M-operand is
  // wave-uniform -> broadcast. 12-float sliding register window.
  {
    const int wave = tid >> 6;
    const int lane = tid & 63;
    const int lagbase = (wave >> 1) << 8;
    const int k0      = (wave & 1) << 9;
    const float4* M4  = (const float4*)M;
    const float4* M14 = (const float4*)M1;
    const int vb = ((k0 + lagbase) >> 2) + lane;
    float a0 = 0.f, a1 = 0.f, a2 = 0.f, a3 = 0.f;
    float4 c0 = M14[vb];
    #pragma unroll 2
    for (int kc = 0; kc < 512; kc += 8) {
      const int f = (k0 + kc) >> 2;
      const float4 u0 = M4[f];
      const float4 u1 = M4[f + 1];
      const float4 c1 = M14[vb + (kc >> 2) + 1];
      const float4 c2 = M14[vb + (kc >> 2) + 2];
      const float v0=c0.x, v1=c0.y, v2=c0.z, v3=c0.w;
      const float v4=c1.x, v5=c1.y, v6=c1.z, v7=c1.w;
      const float v8=c2.x, v9=c2.y, v10=c2.z;
      a0 += u0.x*v0 + u0.y*v1 + u0.z*v2 + u0.w*v3
          + u1.x*v4 + u1.y*v5 + u1.z*v6 + u1.w*v7;
      a1 += u0.x*v1 + u0.y*v2 + u0.z*v3 + u0.w*v4
          + u1.x*v5 + u1.y*v6 + u1.z*v7 + u1.w*v8;
      a2 += u0.x*v2 + u0.y*v3 + u0.z*v4 + u0.w*v5
          + u1.x*v6 + u1.y*v7 + u1.z*v8 + u1.w*v9;
      a3 += u0.x*v3 + u0.y*v4 + u0.z*v5 + u0.w*v6
          + u1.x*v7 + u1.y*v8 + u1.z*v9 + u1.w*v10;
      c0 = c2;
    }
    ((float4*)(Racc + (wave << 8)))[lane] = make_float4(a0, a1, a2, a3);
  }
  __syncthreads();

  // reduce the two k-halves; mask lag 512 (valid lags are 1..511)
  for (int idx = tid; idx < 512; idx += 256) {
    const int h = idx >> 8, i = idx & 255;
    float s = Racc[(h << 1) * 256 + i] + Racc[((h << 1) + 1) * 256 + i];
    R[idx + 1] = (idx == 511) ? 0.0f : s;
  }
  __syncthreads();

  // ---- peak detect: exists i in [2,511] with R[i] > R[i-1] && R[i] > R[i+1]
  {
    int cond = 0;
    for (int i2 = 2 + tid; i2 < 512; i2 += 256) {
      const float c0 = R[i2];
      if (c0 > R[i2 - 1] && c0 > R[i2 + 1]) cond = 1;
    }
    if (__any(cond)) {
      if ((tid & 63) == 0) hasPeak = 1;
    }
  }
  __syncthreads();
  if (tid == 0) f0[t] = hasPeak ? 50.0f : 0.0f;
}

// Median-of-5 smoothing with edge clamp (jnp.pad mode='edge').
__global__ __launch_bounds__(256) void median5_kernel(const float* __restrict__ f0,
                                                      float* __restrict__ out, int T) {
  const int t = blockIdx.x * blockDim.x + threadIdx.x;
  if (t >= T) return;
  float v[5];
  #pragma unroll
  for (int m = 0; m < 5; ++m) {
    int idx = t + m - 2;
    idx = idx < 0 ? 0 : (idx > T - 1 ? T - 1 : idx);
    v[m] = f0[idx];
  }
  #define SW(a,b) { float lo = fminf(v[a], v[b]); float hi = fmaxf(v[a], v[b]); v[a] = lo; v[b] = hi; }
  SW(0,1); SW(3,4); SW(2,4); SW(2,3); SW(1,4); SW(0,3); SW(0,2); SW(1,3); SW(1,2);
  #undef SW
  out[t] = v[2];
}

extern "C" void kernel_launch(void* const* d_in, const int* in_sizes, int n_in,
                              void* d_out, int out_size, void* d_ws, size_t ws_size,
                              hipStream_t stream) {
  const float* audio = (const float*)d_in[0];
  const int n = in_sizes[0];          // 2097152
  const int T = n / HOP + 1;          // 8193

  float* ws  = (float*)d_ws;
  float* f0  = ws;                    // [0, 8193)
  float* win = ws + 8200;             // [8200, 10248)  16B-aligned
  float* twc = ws + 10248;            // 512
  float* tws = ws + 10760;            // 512
  float* unc = ws + 11272;            // 513
  float* uns = ws + 11788;            // 513

  precompute<<<8, 256, 0, stream>>>(win, twc, tws, unc, uns);
  pitch_main<<<T, 256, 0, stream>>>(audio, n, f0, win, twc, tws, unc, uns);
  median5_kernel<<<(T + 255) / 256, 256, 0, stream>>>(f0, (float*)d_out, T);
}

// Round 4
// 186.431 us; speedup vs baseline: 4.2329x; 2.0819x over previous
//
#include <hip/hip_runtime.h>
#include <math.h>

#define HOP 256
#define NFFT 2048
#define PI2F 6.28318530717958647692f
// bank-spread padding: injective, spreads strided patterns across banks
#define PADI(i) ((i) + ((i) >> 5))

// ---------------- one-time tables (recomputed every launch into d_ws) --------
__global__ __launch_bounds__(256) void precompute(float* __restrict__ win,
                                                  float* __restrict__ twc,
                                                  float* __restrict__ tws,
                                                  float* __restrict__ unc,
                                                  float* __restrict__ uns) {
  const int i = blockIdx.x * blockDim.x + threadIdx.x;
  if (i < 2048) win[i] = 0.5f * (1.0f - cosf(PI2F * (float)i / 2048.0f));
  if (i < 512) {
    float s, c;
    sincosf(-PI2F * (float)i / 1024.0f, &s, &c);
    twc[i] = c; tws[i] = s;
  }
  if (i < 513) {
    float s, c;
    sincosf(-PI2F * (float)i / 2048.0f, &s, &c);
    unc[i] = c; uns[i] = s;
  }
}

// 1024-pt radix-2 DIF complex FFT in LDS (padded addressing, bit-rev output).
__device__ __forceinline__ void fft1024(float* __restrict__ z_re,
                                        float* __restrict__ z_im,
                                        const float* __restrict__ twc,
                                        const float* __restrict__ tws,
                                        int tid) {
  for (int lg = 10; lg >= 1; --lg) {
    const int half  = 1 << (lg - 1);
    const int tstep = 1024 >> lg;
    #pragma unroll 2
    for (int b = tid; b < 512; b += 256) {
      const int j  = b & (half - 1);
      const int i0 = ((b >> (lg - 1)) << lg) + j;
      const int a0 = PADI(i0);
      const int a1 = PADI(i0 + half);
      float ur = z_re[a0], ui = z_im[a0];
      float vr = z_re[a1], vi = z_im[a1];
      z_re[a0] = ur + vr; z_im[a0] = ui + vi;
      float dr = ur - vr, di = ui - vi;
      const int twi = PADI(j * tstep);
      float c = twc[twi], s = tws[twi];
      z_re[a1] = dr * c - di * s;
      z_im[a1] = dr * s + di * c;
    }
    __syncthreads();
  }
}

// Fused per frame: window -> |rfft2048| (pass1) -> |rfft2048(M)|^2 (pass2)
// -> Re FFT2048(P) = 2048*autocorr (pass3, P real-even) -> peak -> f0[t].
__global__ __launch_bounds__(256) void pitch_main(const float* __restrict__ audio,
                                                  int n, float* __restrict__ f0,
                                                  const float* __restrict__ gwin,
                                                  const float* __restrict__ gtwc,
                                                  const float* __restrict__ gtws,
                                                  const float* __restrict__ gunc,
                                                  const float* __restrict__ guns) {
  const int t   = blockIdx.x;
  const int tid = threadIdx.x;

  // pooled LDS: 6256 floats = 25.0 KB -> 6 blocks/CU
  __shared__ float pool[6256];
  __shared__ int   hasPeak;
  float* z_re = pool;          // [0,1056)    PADI(1023)=1054
  float* z_im = pool + 1056;   // [1056,2112)
  float* twc  = pool + 2112;   // [2112,2640) PADI(511)=526
  float* tws  = pool + 2640;   // [2640,3168)
  float* unc  = pool + 3168;   // [3168,3684) 513 used
  float* uns  = pool + 3684;   // [3684,4200)
  float* M    = pool + 4200;   // [4200,5228) magnitudes 0..1024
  float* P    = pool + 5228;   // [5228,6256) power spectrum of M, 0..1024
  float* R    = pool + 4200;   // overlays M (dead after pass-2 pack): R[1..512]

  // ---- stage tables ----
  for (int m = tid; m < 512; m += 256) {
    twc[PADI(m)] = gtwc[m];
    tws[PADI(m)] = gtws[m];
  }
  for (int k = tid; k < 513; k += 256) { unc[k] = gunc[k]; uns[k] = guns[k]; }
  if (tid == 0) hasPeak = 0;

  // ---- pass-1 pack: z[i] = x[2i]*w + j*x[2i+1]*w (reflect pad at edges) ----
  const int base = t * HOP - (NFFT / 2);
  if (base >= 0 && base + NFFT <= n) {
    const float2* au2 = (const float2*)(audio + base);
    const float2* wi2 = (const float2*)gwin;
    #pragma unroll 4
    for (int i = tid; i < 1024; i += 256) {
      const float2 a = au2[i];
      const float2 w = wi2[i];
      z_re[PADI(i)] = a.x * w.x;
      z_im[PADI(i)] = a.y * w.y;
    }
  } else {
    for (int i = tid; i < 1024; i += 256) {
      int j0 = base + 2 * i, j1 = base + 2 * i + 1;
      j0 = (j0 < 0) ? -j0 : j0; j0 = (j0 >= n) ? (2 * n - 2 - j0) : j0;
      j1 = (j1 < 0) ? -j1 : j1; j1 = (j1 >= n) ? (2 * n - 2 - j1) : j1;
      z_re[PADI(i)] = audio[j0] * gwin[2 * i];
      z_im[PADI(i)] = audio[j1] * gwin[2 * i + 1];
    }
  }
  __syncthreads();

  fft1024(z_re, z_im, twc, tws, tid);

  // ---- pass-1 untangle -> magnitudes M[0..1024] ----
  #pragma unroll 2
  for (int k = tid; k < 512; k += 256) {
    const int m  = (1024 - k) & 1023;
    const int pk = PADI((int)(__brev((unsigned)k) >> 22));
    const int pm = PADI((int)(__brev((unsigned)m) >> 22));
    const float ar = z_re[pk], ai = z_im[pk];
    const float br = z_re[pm], bi = z_im[pm];
    const float Er = 0.5f * (ar + br), Ei = 0.5f * (ai - bi);
    const float Or = 0.5f * (ai + bi), Oi = 0.5f * (br - ar);
    const float c = unc[k], s = uns[k];
    const float Xr = Er + c * Or - s * Oi;
    const float Xi = Ei + c * Oi + s * Or;
    M[k] = sqrtf(Xr * Xr + Xi * Xi);
    const float Yr = Er - c * Or + s * Oi;
    const float Yi = -Ei + c * Oi + s * Or;
    M[1024 - k] = sqrtf(Yr * Yr + Yi * Yi);
  }
  if (tid == 0) {                       // bin 512: X = conj-rotated Z[bitrev(512)]
    const float x = z_re[PADI(1)], y = z_im[PADI(1)];
    M[512] = sqrtf(x * x + y * y);
  }
  __syncthreads();

  // ---- pass-2 pack: z[i] = M[2i] + j*M[2i+1] (M zero past 1024) ----
  {
    const float2* M2 = (const float2*)M;
    #pragma unroll 4
    for (int i = tid; i < 1024; i += 256) {
      float a = 0.0f, b = 0.0f;
      if (i < 512)       { const float2 mm = M2[i]; a = mm.x; b = mm.y; }
      else if (i == 512) { a = M[1024]; }
      z_re[PADI(i)] = a; z_im[PADI(i)] = b;
    }
  }
  __syncthreads();

  fft1024(z_re, z_im, twc, tws, tid);

  // ---- pass-2 untangle -> P[k] = |RFFT2048(M)[k]|^2, k = 0..1024 ----
  #pragma unroll 2
  for (int k = tid; k < 512; k += 256) {
    const int m  = (1024 - k) & 1023;
    const int pk = PADI((int)(__brev((unsigned)k) >> 22));
    const int pm = PADI((int)(__brev((unsigned)m) >> 22));
    const float ar = z_re[pk], ai = z_im[pk];
    const float br = z_re[pm], bi = z_im[pm];
    const float Er = 0.5f * (ar + br), Ei = 0.5f * (ai - bi);
    const float Or = 0.5f * (ai + bi), Oi = 0.5f * (br - ar);
    const float c = unc[k], s = uns[k];
    const float Xr = Er + c * Or - s * Oi;
    const float Xi = Ei + c * Oi + s * Or;
    P[k] = Xr * Xr + Xi * Xi;
    const float Yr = Er - c * Or + s * Oi;
    const float Yi = -Ei + c * Oi + s * Or;
    P[1024 - k] = Yr * Yr + Yi * Yi;
  }
  if (tid == 0) {
    const float x = z_re[PADI(1)], y = z_im[PADI(1)];
    P[512] = x * x + y * y;
  }
  __syncthreads();

  // ---- pass-3 pack: z[i] = P[2i] + j*P[2i+1], P extended evenly (real-even) ----
  #pragma unroll 4
  for (int i = tid; i < 1024; i += 256) {
    const int e0 = 2 * i, e1 = 2 * i + 1;
    const float a = P[(e0 <= 1024) ? e0 : 2048 - e0];
    const float b = P[(e1 <= 1024) ? e1 : 2048 - e1];
    z_re[PADI(i)] = a; z_im[PADI(i)] = b;
  }
  __syncthreads();

  fft1024(z_re, z_im, twc, tws, tid);

  // ---- pass-3 untangle (real part only): R[l] = Re RFFT2048(P)[l] = 2048*r[l]
  #pragma unroll 2
  for (int l = tid; l < 512; l += 256) {
    if (l >= 1) {
      const int m  = 1024 - l;
      const int pk = PADI((int)(__brev((unsigned)l) >> 22));
      const int pm = PADI((int)(__brev((unsigned)m) >> 22));
      const float ar = z_re[pk], ai = z_im[pk];
      const float br = z_re[pm], bi = z_im[pm];
      const float Er = 0.5f * (ar + br);
      const float Or = 0.5f * (ai + bi), Oi = 0.5f * (br - ar);
      R[l] = Er + unc[l] * Or - uns[l] * Oi;
    }
  }
  if (tid == 0) R[512] = 0.0f;   // lag-512 masked (valid lags 1..511)
  __syncthreads();

  // ---- peak detect: exists i in [2,511] with R[i] > R[i-1] && R[i] > R[i+1]
  {
    int cond = 0;
    for (int i2 = 2 + tid; i2 < 512; i2 += 256) {
      const float c0 = R[i2];
      if (c0 > R[i2 - 1] && c0 > R[i2 + 1]) cond = 1;
    }
    if (__any(cond)) {
      if ((tid & 63) == 0) hasPeak = 1;
    }
  }
  __syncthreads();
  if (tid == 0) f0[t] = hasPeak ? 50.0f : 0.0f;
}

// Median-of-5 smoothing with edge clamp (jnp.pad mode='edge').
__global__ __launch_bounds__(256) void median5_kernel(const float* __restrict__ f0,
                                                      float* __restrict__ out, int T) {
  const int t = blockIdx.x * blockDim.x + threadIdx.x;
  if (t >= T) return;
  float v[5];
  #pragma unroll
  for (int m = 0; m < 5; ++m) {
    int idx = t + m - 2;
    idx = idx < 0 ? 0 : (idx > T - 1 ? T - 1 : idx);
    v[m] = f0[idx];
  }
  #define SW(a,b) { float lo = fminf(v[a], v[b]); float hi = fmaxf(v[a], v[b]); v[a] = lo; v[b] = hi; }
  SW(0,1); SW(3,4); SW(2,4); SW(2,3); SW(1,4); SW(0,3); SW(0,2); SW(1,3); SW(1,2);
  #undef SW
  out[t] = v[2];
}

extern "C" void kernel_launch(void* const* d_in, const int* in_sizes, int n_in,
                              void* d_out, int out_size, void* d_ws, size_t ws_size,
                              hipStream_t stream) {
  const float* audio = (const float*)d_in[0];
  const int n = in_sizes[0];          // 2097152
  const int T = n / HOP + 1;          // 8193

  float* ws  = (float*)d_ws;
  float* f0  = ws;                    // [0, 8193)
  float* win = ws + 8200;             // 2048, 16B-aligned
  float* twc = ws + 10248;            // 512
  float* tws = ws + 10760;            // 512
  float* unc = ws + 11272;            // 513
  float* uns = ws + 11788;            // 513

  precompute<<<8, 256, 0, stream>>>(win, twc, tws, unc, uns);
  pitch_main<<<T, 256, 0, stream>>>(audio, n, f0, win, twc, tws, unc, uns);
  median5_kernel<<<(T + 255) / 256, 256, 0, stream>>>(f0, (float*)d_out, T);
}

// Round 5
// 138.116 us; speedup vs baseline: 5.7136x; 1.3498x over previous
//
#include <hip/hip_runtime.h>
#include <math.h>

#define HOP 256
#define PI2F 6.28318530717958647692f
// float2-element padding: bank period is 16 float2 (128B = 32 banks)
#define PADZ(i) ((i) + ((i) >> 4))
#define PADT(i) ((i) + ((i) >> 4))

// ---------------- one-time tables (recomputed every launch into d_ws) --------
// win[2048]: periodic Hann; tw[512]: e^{-j2pi m/1024}; uw[513]: e^{-j2pi k/2048}
__global__ __launch_bounds__(256) void precompute(float* __restrict__ win,
                                                  float2* __restrict__ tw,
                                                  float2* __restrict__ uw) {
  const int i = blockIdx.x * blockDim.x + threadIdx.x;
  if (i < 2048) win[i] = 0.5f * (1.0f - cosf(PI2F * (float)i / 2048.0f));
  if (i < 512) {
    float s, c; sincosf(-PI2F * (float)i / 1024.0f, &s, &c);
    tw[i] = make_float2(c, s);
  }
  if (i < 513) {
    float s, c; sincosf(-PI2F * (float)i / 2048.0f, &s, &c);
    uw[i] = make_float2(c, s);
  }
}

// base-4 digit reversal of a 10-bit index (position of Z[k] after DIF radix-4)
__device__ __forceinline__ int rev4_10(int k) {
  unsigned x = __brev((unsigned)k) >> 22;                 // 10-bit bit reversal
  return (int)(((x & 0x155u) << 1) | ((x & 0x2AAu) >> 1)); // fix bits in pairs
}

// 1024-pt radix-4 DIF complex FFT in LDS. One butterfly per thread per stage.
// Output in base-4 digit-reversed order.
__device__ __forceinline__ void fft1024_r4(float2* __restrict__ z,
                                           const float2* __restrict__ tw,
                                           int tid) {
  #pragma unroll
  for (int s = 0; s < 4; ++s) {
    const int lq = 8 - 2 * s;                 // log2(quarter)
    const int q  = 1 << lq;
    const int j  = tid & (q - 1);
    const int i0 = ((tid >> lq) << (lq + 2)) + j;
    const int a0 = PADZ(i0), a1 = PADZ(i0 + q), a2 = PADZ(i0 + 2 * q), a3 = PADZ(i0 + 3 * q);
    const float2 a = z[a0], b = z[a1], c = z[a2], d = z[a3];
    const float t0r = a.x + c.x, t0i = a.y + c.y;
    const float t1r = a.x - c.x, t1i = a.y - c.y;
    const float t2r = b.x + d.x, t2i = b.y + d.y;
    const float t3r = b.y - d.y, t3i = d.x - b.x;   // -j*(b-d)
    const int m1 = j << (2 * s);
    const float2 w1 = tw[PADT(m1)];
    const float2 w2 = tw[PADT(2 * m1)];
    const float w3r = w1.x * w2.x - w1.y * w2.y;    // w3 = w1*w2
    const float w3i = w1.x * w2.y + w1.y * w2.x;
    z[a0] = make_float2(t0r + t2r, t0i + t2i);      // B0
    const float b1r = t1r + t3r, b1i = t1i + t3i;   // B1 = (t1 - j t3) * w1
    z[a1] = make_float2(b1r * w1.x - b1i * w1.y, b1r * w1.y + b1i * w1.x);
    const float b2r = t0r - t2r, b2i = t0i - t2i;   // B2 = (t0 - t2) * w2
    z[a2] = make_float2(b2r * w2.x - b2i * w2.y, b2r * w2.y + b2i * w2.x);
    const float b3r = t1r - t3r, b3i = t1i - t3i;   // B3 = (t1 + j t3) * w3
    z[a3] = make_float2(b3r * w3r - b3i * w3i, b3r * w3i + b3i * w3r);
    __syncthreads();
  }
  { // final stage: L=4, all twiddles = 1
    const int i0 = tid << 2;
    const int a0 = PADZ(i0), a1 = PADZ(i0 + 1), a2 = PADZ(i0 + 2), a3 = PADZ(i0 + 3);
    const float2 a = z[a0], b = z[a1], c = z[a2], d = z[a3];
    const float t0r = a.x + c.x, t0i = a.y + c.y;
    const float t1r = a.x - c.x, t1i = a.y - c.y;
    const float t2r = b.x + d.x, t2i = b.y + d.y;
    const float t3r = b.y - d.y, t3i = d.x - b.x;
    z[a0] = make_float2(t0r + t2r, t0i + t2i);
    z[a1] = make_float2(t1r + t3r, t1i + t3i);
    z[a2] = make_float2(t0r - t2r, t0i - t2i);
    z[a3] = make_float2(t1r - t3r, t1i - t3i);
    __syncthreads();
  }
}

// Fused per frame: window -> |rfft2048| (pass1) -> |rfft2048(M)|^2 (pass2)
// -> Re FFT2048(P) = 2048*autocorr (pass3, P real-even) -> peak -> f0[t].
__global__ __launch_bounds__(256) void pitch_main(const float* __restrict__ audio,
                                                  int n, float* __restrict__ f0,
                                                  const float* __restrict__ gwin,
                                                  const float2* __restrict__ gtw,
                                                  const float2* __restrict__ guw) {
  const int t   = blockIdx.x;
  const int tid = threadIdx.x;

  __shared__ float2 z[1088];            // PADZ(1023)=1086
  __shared__ float2 tw[545];            // PADT(511)=542
  __shared__ float2 uw[513];
  __shared__ __align__(16) float M[1026];
  __shared__ __align__(16) float P[1026];
  __shared__ int hasPeak;
  float* R = M;                         // overlay: M dead after pass-2 pack

  // ---- stage tables ----
  for (int m = tid; m < 512; m += 256) tw[PADT(m)] = gtw[m];
  for (int k = tid; k < 513; k += 256) uw[k] = guw[k];
  if (tid == 0) hasPeak = 0;

  // ---- pass-1 pack: z[i] = x[2i]*w + j*x[2i+1]*w (reflect pad at edges) ----
  const int base = t * HOP - 1024;
  if (base >= 0 && base + 2048 <= n) {
    const float2* au2 = (const float2*)(audio + base);
    const float2* wi2 = (const float2*)gwin;
    #pragma unroll 4
    for (int i = tid; i < 1024; i += 256) {
      const float2 a = au2[i];
      const float2 w = wi2[i];
      z[PADZ(i)] = make_float2(a.x * w.x, a.y * w.y);
    }
  } else {
    for (int i = tid; i < 1024; i += 256) {
      int j0 = base + 2 * i, j1 = base + 2 * i + 1;
      j0 = (j0 < 0) ? -j0 : j0; j0 = (j0 >= n) ? (2 * n - 2 - j0) : j0;
      j1 = (j1 < 0) ? -j1 : j1; j1 = (j1 >= n) ? (2 * n - 2 - j1) : j1;
      z[PADZ(i)] = make_float2(audio[j0] * gwin[2 * i], audio[j1] * gwin[2 * i + 1]);
    }
  }
  __syncthreads();

  fft1024_r4(z, tw, tid);

  // ---- pass-1 untangle -> magnitudes M[0..1024] ----
  for (int k = tid; k < 513; k += 256) {
    const int m = (1024 - k) & 1023;
    const float2 Zk = z[PADZ(rev4_10(k))];
    const float2 Zm = z[PADZ(rev4_10(m))];
    const float Er = 0.5f * (Zk.x + Zm.x), Ei = 0.5f * (Zk.y - Zm.y);
    const float Or = 0.5f * (Zk.y + Zm.y), Oi = 0.5f * (Zm.x - Zk.x);
    const float2 w = uw[k];
    const float Xr = Er + w.x * Or - w.y * Oi;
    const float Xi = Ei + w.x * Oi + w.y * Or;
    M[k] = sqrtf(Xr * Xr + Xi * Xi);
    const float Yr = Er - w.x * Or + w.y * Oi;
    const float Yi = -Ei + w.x * Oi + w.y * Or;
    M[1024 - k] = sqrtf(Yr * Yr + Yi * Yi);
  }
  __syncthreads();

  // ---- pass-2 pack: z[i] = M[2i] + j*M[2i+1] (M zero past 1024) ----
  {
    const float2* M2 = (const float2*)M;
    #pragma unroll 4
    for (int i = tid; i < 1024; i += 256) {
      float2 v = make_float2(0.0f, 0.0f);
      if (i < 512) v = M2[i];
      else if (i == 512) v = make_float2(M[1024], 0.0f);
      z[PADZ(i)] = v;
    }
  }
  __syncthreads();

  fft1024_r4(z, tw, tid);

  // ---- pass-2 untangle -> P[k] = |RFFT2048(M)[k]|^2 ----
  for (int k = tid; k < 513; k += 256) {
    const int m = (1024 - k) & 1023;
    const float2 Zk = z[PADZ(rev4_10(k))];
    const float2 Zm = z[PADZ(rev4_10(m))];
    const float Er = 0.5f * (Zk.x + Zm.x), Ei = 0.5f * (Zk.y - Zm.y);
    const float Or = 0.5f * (Zk.y + Zm.y), Oi = 0.5f * (Zm.x - Zk.x);
    const float2 w = uw[k];
    const float Xr = Er + w.x * Or - w.y * Oi;
    const float Xi = Ei + w.x * Oi + w.y * Or;
    P[k] = Xr * Xr + Xi * Xi;
    const float Yr = Er - w.x * Or + w.y * Oi;
    const float Yi = -Ei + w.x * Oi + w.y * Or;
    P[1024 - k] = Yr * Yr + Yi * Yi;
  }
  __syncthreads();

  // ---- pass-3 pack: z[i] = Pe[2i] + j*Pe[2i+1], Pe = even extension of P ----
  #pragma unroll 4
  for (int i = tid; i < 1024; i += 256) {
    float2 v;
    if (i < 512)       v = ((const float2*)P)[i];
    else if (i == 512) v = make_float2(P[1024], P[1023]);
    else { const int e0 = 2048 - 2 * i; v = make_float2(P[e0], P[e0 - 1]); }
    z[PADZ(i)] = v;
  }
  __syncthreads();

  fft1024_r4(z, tw, tid);

  // ---- pass-3 untangle (real part): R[l] = Re RFFT2048(P)[l] = 2048*r[l] ----
  for (int l = tid; l < 512; l += 256) {
    if (l >= 1) {
      const int m = 1024 - l;
      const float2 Zk = z[PADZ(rev4_10(l))];
      const float2 Zm = z[PADZ(rev4_10(m))];
      const float Er = 0.5f * (Zk.x + Zm.x);
      const float Or = 0.5f * (Zk.y + Zm.y), Oi = 0.5f * (Zm.x - Zk.x);
      const float2 w = uw[l];
      R[l] = Er + w.x * Or - w.y * Oi;
    }
  }
  if (tid == 0) R[512] = 0.0f;          // lag-512 masked (valid lags 1..511)
  __syncthreads();

  // ---- peak detect: exists i in [2,511] with R[i] > R[i-1] && R[i] > R[i+1]
  {
    int cond = 0;
    for (int i2 = 2 + tid; i2 < 512; i2 += 256) {
      const float c0 = R[i2];
      if (c0 > R[i2 - 1] && c0 > R[i2 + 1]) cond = 1;
    }
    if (__any(cond)) {
      if ((tid & 63) == 0) hasPeak = 1;
    }
  }
  __syncthreads();
  if (tid == 0) f0[t] = hasPeak ? 50.0f : 0.0f;
}

// Median-of-5 smoothing with edge clamp (jnp.pad mode='edge').
__global__ __launch_bounds__(256) void median5_kernel(const float* __restrict__ f0,
                                                      float* __restrict__ out, int T) {
  const int t = blockIdx.x * blockDim.x + threadIdx.x;
  if (t >= T) return;
  float v[5];
  #pragma unroll
  for (int m = 0; m < 5; ++m) {
    int idx = t + m - 2;
    idx = idx < 0 ? 0 : (idx > T - 1 ? T - 1 : idx);
    v[m] = f0[idx];
  }
  #define SW(a,b) { float lo = fminf(v[a], v[b]); float hi = fmaxf(v[a], v[b]); v[a] = lo; v[b] = hi; }
  SW(0,1); SW(3,4); SW(2,4); SW(2,3); SW(1,4); SW(0,3); SW(0,2); SW(1,3); SW(1,2);
  #undef SW
  out[t] = v[2];
}

extern "C" void kernel_launch(void* const* d_in, const int* in_sizes, int n_in,
                              void* d_out, int out_size, void* d_ws, size_t ws_size,
                              hipStream_t stream) {
  const float* audio = (const float*)d_in[0];
  const int n = in_sizes[0];          // 2097152
  const int T = n / HOP + 1;          // 8193

  float* ws   = (float*)d_ws;
  float* f0   = ws;                   // [0, 8193)
  float* win  = ws + 8200;            // 2048 floats, 16B-aligned
  float2* tw  = (float2*)(ws + 10248);// 512 float2
  float2* uw  = (float2*)(ws + 11272);// 513 float2

  precompute<<<8, 256, 0, stream>>>(win, tw, uw);
  pitch_main<<<T, 256, 0, stream>>>(audio, n, f0, win, tw, uw);
  median5_kernel<<<(T + 255) / 256, 256, 0, stream>>>(f0, (float*)d_out, T);
}

// Round 6
// 121.369 us; speedup vs baseline: 6.5020x; 1.1380x over previous
//
#include <hip/hip_runtime.h>
#include <math.h>

#define HOP 256
#define PI2F 6.28318530717958647692f
#define PADZ(i) ((i) + ((i) >> 4))

#define C16 0.92387953251128675613f   // cos(pi/8)
#define S16 0.38268343236508977173f   // sin(pi/8)
#define RH  0.70710678118654752440f   // sqrt(2)/2

// wave-internal LDS ordering fence (DS ops are per-wave in-order; this is belt+braces
// against any compiler/HW reordering): drain LDS queue, pin scheduler.
#define FENCE() do { asm volatile("s_waitcnt lgkmcnt(0)" ::: "memory"); \
                     __builtin_amdgcn_sched_barrier(0); } while (0)

// ---------------- one-time tables (recomputed every launch into d_ws) --------
// win[2048]: periodic Hann; gtw[512]: e^{-j2pi m/1024}; guw[513]: e^{-j2pi k/2048}
__global__ __launch_bounds__(256) void precompute(float* __restrict__ win,
                                                  float2* __restrict__ gtw,
                                                  float2* __restrict__ guw) {
  const int i = blockIdx.x * blockDim.x + threadIdx.x;
  if (i < 2048) win[i] = 0.5f * (1.0f - cosf(PI2F * (float)i / 2048.0f));
  if (i < 512) {
    float s, c; sincosf(-PI2F * (float)i / 1024.0f, &s, &c);
    gtw[i] = make_float2(c, s);
  }
  if (i < 513) {
    float s, c; sincosf(-PI2F * (float)i / 2048.0f, &s, &c);
    guw[i] = make_float2(c, s);
  }
}

// ---------------- complex helpers (forward convention w16 = e^{-j2pi/16}) ----
__device__ __forceinline__ float2 cadd(float2 a, float2 b){ return make_float2(a.x+b.x, a.y+b.y); }
__device__ __forceinline__ float2 csub(float2 a, float2 b){ return make_float2(a.x-b.x, a.y-b.y); }
__device__ __forceinline__ float2 cmul(float2 a, float2 b){
  return make_float2(fmaf(a.x, b.x, -a.y*b.y), fmaf(a.x, b.y, a.y*b.x));
}
__device__ __forceinline__ float2 mul_mj(float2 v){ return make_float2(v.y, -v.x); }  // *(-j)
__device__ __forceinline__ float2 mul_pj(float2 v){ return make_float2(-v.y, v.x); }  // *(+j)
// multiply by w16^e
__device__ __forceinline__ float2 tw1f(float2 v){ return make_float2(fmaf(C16,v.x, S16*v.y), fmaf(C16,v.y,-S16*v.x)); }
__device__ __forceinline__ float2 tw2f(float2 v){ return make_float2(RH*(v.x+v.y), RH*(v.y-v.x)); }
__device__ __forceinline__ float2 tw3f(float2 v){ return make_float2(fmaf(S16,v.x, C16*v.y), fmaf(S16,v.y,-C16*v.x)); }
__device__ __forceinline__ float2 tw4f(float2 v){ return make_float2(v.y, -v.x); }
__device__ __forceinline__ float2 tw6f(float2 v){ return make_float2(RH*(v.y-v.x), -RH*(v.x+v.y)); }
__device__ __forceinline__ float2 tw9f(float2 v){ return make_float2(fmaf(-C16,v.x,-S16*v.y), fmaf(S16,v.x,-C16*v.y)); }

__device__ __forceinline__ void dft4(float2 a, float2 b, float2 c, float2 d,
                                     float2& o0, float2& o1, float2& o2, float2& o3) {
  const float2 t0 = cadd(a, c), t1 = csub(a, c);
  const float2 t2 = cadd(b, d), t3 = csub(b, d);
  o0 = cadd(t0, t2);
  o2 = csub(t0, t2);
  o1 = cadd(t1, mul_mj(t3));
  o3 = cadd(t1, mul_pj(t3));
}

// in-place 16-pt DFT: v[k] = sum_j v_in[j] * w16^{jk}
__device__ __forceinline__ void dft16(float2 v[16]) {
  float2 A0[4], A1[4], A2[4], A3[4];                       // A{j0}[p]
  dft4(v[0], v[4], v[ 8], v[12], A0[0], A0[1], A0[2], A0[3]);
  dft4(v[1], v[5], v[ 9], v[13], A1[0], A1[1], A1[2], A1[3]);
  dft4(v[2], v[6], v[10], v[14], A2[0], A2[1], A2[2], A2[3]);
  dft4(v[3], v[7], v[11], v[15], A3[0], A3[1], A3[2], A3[3]);
  dft4(A0[0],       A1[0],        A2[0],        A3[0],       v[0], v[4], v[ 8], v[12]); // p=0
  dft4(A0[1], tw1f(A1[1]), tw2f(A2[1]), tw3f(A3[1]), v[1], v[5], v[ 9], v[13]); // p=1, e=0,1,2,3
  dft4(A0[2], tw2f(A1[2]), tw4f(A2[2]), tw6f(A3[2]), v[2], v[6], v[10], v[14]); // p=2, e=0,2,4,6
  dft4(A0[3], tw3f(A1[3]), tw6f(A2[3]), tw9f(A3[3]), v[3], v[7], v[11], v[15]); // p=3, e=0,3,6,9
}

// 1024-pt FFT for ONE wave: input v[j] = x[l + 64 j]; output natural-order Z in
// zw[PADZ(k)]. Decomposition 1024 = 16 x 16 x 4, two LDS exchanges.
__device__ __forceinline__ void wave_fft1024(float2* __restrict__ zw, float2 v[16],
                                             const int l, const float2* __restrict__ gtw) {
  // stage A: z_s[l] = w1024^{l s} * sum_j x[l+64j] w16^{js}
  dft16(v);
  {
    const float2 w1 = gtw[l];
    float2 w = w1;
    #pragma unroll
    for (int s = 1; s < 16; ++s) { v[s] = cmul(v[s], w); w = cmul(w, w1); }
  }
  // exchange 1: E[s][l] at 65 s + l  (per-instr stride-1 -> bank floor)
  #pragma unroll
  for (int s = 0; s < 16; ++s) zw[65 * s + l] = v[s];
  FENCE();
  const int sp = l >> 2, n0 = l & 3;
  #pragma unroll
  for (int r = 0; r < 16; ++r) v[r] = zw[65 * sp + n0 + 4 * r];
  // stage B: g_u = w64^{n0 u} * sum_r z_sp[n0+4r] w16^{ru}
  dft16(v);
  {
    const float2 wb = gtw[n0 << 4];
    float2 w = wb;
    #pragma unroll
    for (int u = 1; u < 16; ++u) { v[u] = cmul(v[u], w); w = cmul(w, wb); }
  }
  // exchange 2: E2[sp][u][n0] at 65 sp + 4u + n0
  #pragma unroll
  for (int u = 0; u < 16; ++u) zw[65 * sp + 4 * u + n0] = v[u];
  FENCE();
  #pragma unroll
  for (int b = 0; b < 4; ++b)
    #pragma unroll
    for (int m0 = 0; m0 < 4; ++m0)
      v[4 * b + m0] = zw[65 * sp + 16 * n0 + 4 * b + m0];  // h[b][m0], a = n0
  FENCE();   // all reads retired before stores overwrite the buffer
  // final radix-4 over m0: Z[256 q2 + 64 a + 16 b + sp]
  #pragma unroll
  for (int b = 0; b < 4; ++b) {
    float2 o0, o1, o2, o3;
    dft4(v[4*b+0], v[4*b+1], v[4*b+2], v[4*b+3], o0, o1, o2, o3);
    const int kb = 64 * n0 + 16 * b + sp;
    zw[PADZ(kb      )] = o0;
    zw[PADZ(kb + 256)] = o1;
    zw[PADZ(kb + 512)] = o2;
    zw[PADZ(kb + 768)] = o3;
  }
  FENCE();
}

// untangle rfft2048 from packed Z.  MODE 0: mp[k]=|X[k]| ; 1: mp[k]=|X[k]|^2 ;
// 2: mp[k]=Re X[k] for k in 1..511, mp[512]=0.
template<int MODE>
__device__ __forceinline__ void untangle(const float2* __restrict__ zw,
                                         float* __restrict__ mp, const int l,
                                         const float2* __restrict__ guw) {
  #pragma unroll
  for (int c = 0; c < 8; ++c) {
    const int k = l + 64 * c;                 // 0..511
    const int m = (1024 - k) & 1023;
    const float2 Zk = zw[PADZ(k)];
    const float2 Zm = zw[PADZ(m)];
    const float Er = 0.5f * (Zk.x + Zm.x), Ei = 0.5f * (Zk.y - Zm.y);
    const float Or = 0.5f * (Zk.y + Zm.y), Oi = 0.5f * (Zm.x - Zk.x);
    const float2 w = guw[k];
    const float wOr = w.x * Or - w.y * Oi;
    const float wOi = w.x * Oi + w.y * Or;
    if (MODE == 2) {
      if (k >= 1) mp[k] = Er + wOr;
    } else {
      const float Xr = Er + wOr, Xi =  Ei + wOi;
      const float Yr = Er - wOr, Yi = -Ei + wOi;
      if (MODE == 0) {
        mp[k]        = sqrtf(Xr * Xr + Xi * Xi);
        mp[1024 - k] = sqrtf(Yr * Yr + Yi * Yi);
      } else {
        mp[k]        = Xr * Xr + Xi * Xi;
        mp[1024 - k] = Yr * Yr + Yi * Yi;
      }
    }
  }
  if (l == 0) {            // bin 512: |X[512]| = |Z[512]| ; R[512] masked to 0
    const float2 Z5 = zw[PADZ(512)];
    if (MODE == 0)      mp[512] = sqrtf(Z5.x * Z5.x + Z5.y * Z5.y);
    else if (MODE == 1) mp[512] = Z5.x * Z5.x + Z5.y * Z5.y;
    else                mp[512] = 0.0f;
  }
}

// Fused: one WAVE per frame; no __syncthreads anywhere.
__global__ __launch_bounds__(256, 3) void pitch_main(const float* __restrict__ audio,
    int N, int T, float* __restrict__ f0,
    const float* __restrict__ gwin, const float2* __restrict__ gtw,
    const float2* __restrict__ guw) {
  __shared__ float2 zbuf[4][1088];     // per-wave FFT workspace (PADZ(1023)=1086)
  __shared__ float  mpbuf[4][1028];    // per-wave M -> P -> R overlay
  const int wv = threadIdx.x >> 6;
  const int l  = threadIdx.x & 63;
  const int frame = blockIdx.x * 4 + wv;
  if (frame >= T) return;
  float2* zw = zbuf[wv];
  float*  mp = mpbuf[wv];
  float2  v[16];

  // ---- pass 1: window + pack x[i] = a[2i] w[2i] + j a[2i+1] w[2i+1] ----
  const int base = frame * HOP - 1024;
  if (base >= 0 && base + 2048 <= N) {
    const float2* au2 = (const float2*)(audio + base);
    const float2* wi2 = (const float2*)gwin;
    #pragma unroll
    for (int j = 0; j < 16; ++j) {
      const float2 a = au2[l + 64 * j];
      const float2 w = wi2[l + 64 * j];
      v[j] = make_float2(a.x * w.x, a.y * w.y);
    }
  } else {                                     // 8 edge frames: reflect pad
    #pragma unroll
    for (int j = 0; j < 16; ++j) {
      const int i2 = 2 * (l + 64 * j);
      int j0 = base + i2, j1 = base + i2 + 1;
      j0 = (j0 < 0) ? -j0 : j0; j0 = (j0 >= N) ? (2 * N - 2 - j0) : j0;
      j1 = (j1 < 0) ? -j1 : j1; j1 = (j1 >= N) ? (2 * N - 2 - j1) : j1;
      v[j] = make_float2(audio[j0] * gwin[i2], audio[j1] * gwin[i2 + 1]);
    }
  }
  wave_fft1024(zw, v, l, gtw);
  untangle<0>(zw, mp, l, guw);                 // M[0..1024]
  FENCE();

  // ---- pass 2: pack z2[i] = M[2i] + j M[2i+1] (M == 0 past 1024) ----
  {
    const float2* mp2 = (const float2*)mp;
    #pragma unroll
    for (int j = 0; j < 8; ++j) v[j] = mp2[l + 64 * j];    // i <= 511
    const float mv = mp[1024];                              // broadcast read
    v[8] = make_float2((l == 0) ? mv : 0.0f, 0.0f);         // i = 512
    #pragma unroll
    for (int j = 9; j < 16; ++j) v[j] = make_float2(0.0f, 0.0f);
  }
  wave_fft1024(zw, v, l, gtw);
  untangle<1>(zw, mp, l, guw);                 // P[0..1024] (overwrites M)
  FENCE();

  // ---- pass 3: pack z3[i] = Pe[2i] + j Pe[2i+1], Pe = even extension ----
  {
    const float2* mp2 = (const float2*)mp;
    #pragma unroll
    for (int j = 0; j < 8; ++j) v[j] = mp2[l + 64 * j];    // i <= 511 direct
    #pragma unroll
    for (int j = 8; j < 16; ++j) {                          // mirrored side
      const int m2 = 1024 - (l + 64 * j);                   // 1..512
      v[j] = make_float2(mp2[m2].x, mp2[m2 - 1].y);
    }
  }
  wave_fft1024(zw, v, l, gtw);
  untangle<2>(zw, mp, l, guw);                 // R[1..512] = 2048*autocorr
  FENCE();

  // ---- peak detect: any i in [2,511] with R[i] > R[i-1] && R[i] > R[i+1] ----
  int cond = 0;
  #pragma unroll
  for (int c = 0; c < 8; ++c) {
    const int k = l + 64 * c;
    if (k >= 2) {                              // k <= 511 always
      const float c0 = mp[k];
      if (c0 > mp[k - 1] && c0 > mp[k + 1]) cond = 1;
    }
  }
  const int has = __any(cond);
  if (l == 0) f0[frame] = has ? 50.0f : 0.0f;
}

// Median-of-5 smoothing with edge clamp (jnp.pad mode='edge').
__global__ __launch_bounds__(256) void median5_kernel(const float* __restrict__ f0,
                                                      float* __restrict__ out, int T) {
  const int t = blockIdx.x * blockDim.x + threadIdx.x;
  if (t >= T) return;
  float v[5];
  #pragma unroll
  for (int m = 0; m < 5; ++m) {
    int idx = t + m - 2;
    idx = idx < 0 ? 0 : (idx > T - 1 ? T - 1 : idx);
    v[m] = f0[idx];
  }
  #define SW(a,b) { float lo = fminf(v[a], v[b]); float hi = fmaxf(v[a], v[b]); v[a] = lo; v[b] = hi; }
  SW(0,1); SW(3,4); SW(2,4); SW(2,3); SW(1,4); SW(0,3); SW(0,2); SW(1,3); SW(1,2);
  #undef SW
  out[t] = v[2];
}

extern "C" void kernel_launch(void* const* d_in, const int* in_sizes, int n_in,
                              void* d_out, int out_size, void* d_ws, size_t ws_size,
                              hipStream_t stream) {
  const float* audio = (const float*)d_in[0];
  const int n = in_sizes[0];          // 2097152
  const int T = n / HOP + 1;          // 8193

  float* ws   = (float*)d_ws;
  float* f0   = ws;                   // [0, 8193)
  float* win  = ws + 8200;            // 2048 floats, 16B-aligned
  float2* gtw = (float2*)(ws + 10248);// 512 float2
  float2* guw = (float2*)(ws + 11272);// 513 float2

  precompute<<<8, 256, 0, stream>>>(win, gtw, guw);
  pitch_main<<<(T + 3) / 4, 256, 0, stream>>>(audio, n, T, f0, win, gtw, guw);
  median5_kernel<<<(T + 255) / 256, 256, 0, stream>>>(f0, (float*)d_out, T);
}